// Round 4
// baseline (396.787 us; speedup 1.0000x reference)
//
#include <hip/hip_runtime.h>
#include <hip/hip_bf16.h>
#include <stdint.h>

#define N_NODES_C 1000000
#define N_GRAPHS_C 4096

typedef __attribute__((ext_vector_type(8))) __bf16 bf16x8;
typedef __attribute__((ext_vector_type(2))) __bf16 bf16x2;
typedef __attribute__((ext_vector_type(4))) float f32x4;

__device__ __forceinline__ unsigned short f2bf(float f) {
    union { float f; unsigned int u; } v; v.f = f;
    unsigned int r = v.u + 0x7FFFu + ((v.u >> 16) & 1u);   // RNE
    return (unsigned short)(r >> 16);
}
__device__ __forceinline__ unsigned int pack2(float a, float b) {
#if __has_builtin(__builtin_amdgcn_cvt_pk_bf16_f32)
    bf16x2 r = __builtin_amdgcn_cvt_pk_bf16_f32(a, b);
    union { bf16x2 v; unsigned int u; } cv; cv.v = r;
    return cv.u;
#else
    return (unsigned int)f2bf(a) | ((unsigned int)f2bf(b) << 16);
#endif
}

// Node kernel, ZERO workspace. Block b owns 256 contiguous nodes (4 chunks of 64;
// each wave does 16 nodes/chunk). Per-block setup (amortized over 256 nodes):
//   - stage full Wn (128x64 fp32, 32 KB) into LDS, coalesced;
//   - fp32 rank-3 bias factorization: M[m][j]=sum_k Wg[m][k]*Wn[64+k][j] (m<3),
//     C0[j]=bn[j]+sum_k bg[k]*Wn[64+k][j]  ->  c[b][j] = C0[j]+sum_m ga[b][m]*M[m][j]
//     (exactly stage0's fp32 c-table, re-associated; no 1 MB c buffer needed);
//   - MFMA B-fragments built from LDS transpose reads + bf16 cvt (replaces BT buffer).
// e = exp(s+ba) written to out[n]; finalized in place by fin_kernel (no e buffer,
// no denom buffer, no atomics, no part[] machinery).
__global__ __launch_bounds__(256, 4) void node_kernel(
    const float* __restrict__ x, const int* __restrict__ nb,
    const float* __restrict__ ga, const float* __restrict__ Wg,
    const float* __restrict__ bg, const float* __restrict__ Wn,
    const float* __restrict__ bn, const float* __restrict__ Wa,
    const float* __restrict__ ba, float* __restrict__ out)
{
    __shared__ float Wns[128 * 64];   // full Wn fp32 (32 KB)
    __shared__ float Ms[4][64];       // rows 0..2 = M[m][j]; row 3 = C0[j]

    int t = threadIdx.x;
    int wave = t >> 6, lane = t & 63;
    int quad = lane >> 4, l15 = lane & 15;
    int blockbase = blockIdx.x * 256;
    int avail = N_NODES_C - blockbase;
    int nIter = (avail >= 256) ? 4 : (avail >> 6);   // tail block: 64-node multiple
    bool is64 = nb[N_NODES_C - 1] < 1024;            // int64 low/high-word layout vs int32

    // ---- setup: Wn -> LDS (2048 float4, 8 per thread, coalesced)
#pragma unroll
    for (int i = 0; i < 8; ++i)
        ((float4*)Wns)[t + i * 256] = ((const float4*)Wn)[t + i * 256];
    __syncthreads();

    // ---- M / C0 (wave-uniform branch: wave 3 computes C0, waves 0-2 compute M)
    {
        int m = t >> 6, j = t & 63;
        float accv;
        if (m == 3) {
            accv = bn[j];
#pragma unroll 16
            for (int k = 0; k < 64; ++k) accv += bg[k] * Wns[(64 + k) * 64 + j];
        } else {
            accv = 0.f;
#pragma unroll 16
            for (int k = 0; k < 64; ++k) accv += Wg[m * 64 + k] * Wns[(64 + k) * 64 + j];
        }
        Ms[m][j] = accv;
    }
    __syncthreads();

    // ---- B fragments from LDS transpose reads: b0[nt] holds Wn[quad*8+jj][nt*16+l15]
    bf16x8 b0[4], b1[4];
#pragma unroll
    for (int nt = 0; nt < 4; ++nt) {
        int n = nt * 16 + l15;
        union { bf16x8 v; unsigned int u[4]; } B;
#pragma unroll
        for (int p = 0; p < 4; ++p)
            B.u[p] = pack2(Wns[(quad * 8 + 2 * p) * 64 + n],
                           Wns[(quad * 8 + 2 * p + 1) * 64 + n]);
        b0[nt] = B.v;
#pragma unroll
        for (int p = 0; p < 4; ++p)
            B.u[p] = pack2(Wns[(32 + quad * 8 + 2 * p) * 64 + n],
                           Wns[(32 + quad * 8 + 2 * p + 1) * 64 + n]);
        b1[nt] = B.v;
    }

    // ---- per-lane invariants: M/C0 slices, Wa, ba
    float Mreg[4][3], C0r[4], wa[4];
#pragma unroll
    for (int nt = 0; nt < 4; ++nt) {
        int n = nt * 16 + l15;
        Mreg[nt][0] = Ms[0][n]; Mreg[nt][1] = Ms[1][n]; Mreg[nt][2] = Ms[2][n];
        C0r[nt] = Ms[3][n];
        wa[nt] = Wa[n];
    }
    float bav = ba[0];

    // ---- main loop: 4 chunks of 64 nodes (16 per wave)
    for (int it = 0; it < nIter; ++it) {
        int base = blockbase + it * 64 + wave * 16;

        // x loads: lane covers row base+l15, 4x dwordx4 in flight
        const float4* xp = (const float4*)(x + (long)(base + l15) * 64);
        float4 v0 = xp[quad * 2];
        float4 v1 = xp[quad * 2 + 1];
        float4 v2 = xp[8 + quad * 2];
        float4 v3 = xp[8 + quad * 2 + 1];

        // segment ids: one coalesced load, distributed by shuffle
        int segown = is64 ? nb[2L * (base + l15)] : nb[base + l15];
        int sg0 = __shfl(segown, quad * 4 + 0, 64);
        int sg1 = __shfl(segown, quad * 4 + 1, 64);
        int sg2 = __shfl(segown, quad * 4 + 2, 64);
        int sg3 = __shfl(segown, quad * 4 + 3, 64);

        union { bf16x8 v; unsigned int u[4]; } A0, A1;
        A0.u[0] = pack2(v0.x, v0.y); A0.u[1] = pack2(v0.z, v0.w);
        A0.u[2] = pack2(v1.x, v1.y); A0.u[3] = pack2(v1.z, v1.w);
        A1.u[0] = pack2(v2.x, v2.y); A1.u[1] = pack2(v2.z, v2.w);
        A1.u[2] = pack2(v3.x, v3.y); A1.u[3] = pack2(v3.z, v3.w);

        f32x4 acc[4];
#pragma unroll
        for (int nt = 0; nt < 4; ++nt) {
            acc[nt] = (f32x4){0.f, 0.f, 0.f, 0.f};
            acc[nt] = __builtin_amdgcn_mfma_f32_16x16x32_bf16(A0.v, b0[nt], acc[nt], 0, 0, 0);
            acc[nt] = __builtin_amdgcn_mfma_f32_16x16x32_bf16(A1.v, b1[nt], acc[nt], 0, 0, 0);
        }

        // graph-attr rows (broadcast loads, L2-resident 48 KB table)
        bool uni = (sg0 == sg3);                 // sorted -> ends equal => all equal
        float a00 = ga[sg0 * 3], a01 = ga[sg0 * 3 + 1], a02 = ga[sg0 * 3 + 2];
        float a10, a11, a12, a20, a21, a22, a30, a31, a32;
        if (uni) {
            a10 = a00; a11 = a01; a12 = a02;
            a20 = a00; a21 = a01; a22 = a02;
            a30 = a00; a31 = a01; a32 = a02;
        } else {
            a10 = ga[sg1 * 3]; a11 = ga[sg1 * 3 + 1]; a12 = ga[sg1 * 3 + 2];
            a20 = ga[sg2 * 3]; a21 = ga[sg2 * 3 + 1]; a22 = ga[sg2 * 3 + 2];
            a30 = ga[sg3 * 3]; a31 = ga[sg3 * 3 + 1]; a32 = ga[sg3 * 3 + 2];
        }

        // epilogue. C/D layout: col = l15 + 16*nt, rows = base + quad*4 + reg
        float sp0 = 0.f, sp1 = 0.f, sp2 = 0.f, sp3 = 0.f;
#pragma unroll
        for (int nt = 0; nt < 4; ++nt) {
            float m0 = Mreg[nt][0], m1 = Mreg[nt][1], m2 = Mreg[nt][2], cc = C0r[nt];
            float y0 = acc[nt].x + cc + a00 * m0 + a01 * m1 + a02 * m2;
            float y1 = acc[nt].y + cc + a10 * m0 + a11 * m1 + a12 * m2;
            float y2 = acc[nt].z + cc + a20 * m0 + a21 * m1 + a22 * m2;
            float y3 = acc[nt].w + cc + a30 * m0 + a31 * m1 + a32 * m2;
            sp0 += __logf(1.f + __expf(y0)) * wa[nt];
            sp1 += __logf(1.f + __expf(y1)) * wa[nt];
            sp2 += __logf(1.f + __expf(y2)) * wa[nt];
            sp3 += __logf(1.f + __expf(y3)) * wa[nt];
        }
#pragma unroll
        for (int off = 1; off < 16; off <<= 1) {   // xor 1,2,4,8 stays inside the quad
            sp0 += __shfl_xor(sp0, off, 64);
            sp1 += __shfl_xor(sp1, off, 64);
            sp2 += __shfl_xor(sp2, off, 64);
            sp3 += __shfl_xor(sp3, off, 64);
        }
        if (l15 == 0) {
            int r0 = base + quad * 4;
            *(float4*)&out[r0] = make_float4(__expf(sp0 + bav), __expf(sp1 + bav),
                                             __expf(sp2 + bav), __expf(sp3 + bav));
        }
    }
}

// Finalize in place, per graph: block g binary-searches its node range in sorted nb,
// tree-reduces denom from out[] (e values), divides in place. No global denom buffer.
__global__ __launch_bounds__(256) void fin_kernel(
    const int* __restrict__ nb, float* __restrict__ out)
{
    int g = blockIdx.x;
    bool is64 = nb[N_NODES_C - 1] < 1024;
    // lower_bound(key): first i with nb[i] >= key. All threads run it redundantly
    // (identical path -> broadcast loads, no divergence).
    int start, end;
    {
        int lo = 0, hi = N_NODES_C;
        while (lo < hi) {
            int mid = (lo + hi) >> 1;
            int v = is64 ? nb[2L * mid] : nb[mid];
            if (v < g) lo = mid + 1; else hi = mid;
        }
        start = lo;
        lo = start; hi = N_NODES_C;
        while (lo < hi) {
            int mid = (lo + hi) >> 1;
            int v = is64 ? nb[2L * mid] : nb[mid];
            if (v < g + 1) lo = mid + 1; else hi = mid;
        }
        end = lo;
    }
    if (end <= start) return;                    // empty graph

    int t = threadIdx.x;
    float s = 0.f;
    for (int i = start + t; i < end; i += 256) s += out[i];
#pragma unroll
    for (int off = 32; off; off >>= 1) s += __shfl_down(s, off, 64);
    __shared__ float wsum[4];
    __shared__ float dsh;
    int lane = t & 63, w = t >> 6;
    if (lane == 0) wsum[w] = s;
    __syncthreads();
    if (t == 0) dsh = wsum[0] + wsum[1] + wsum[2] + wsum[3];
    __syncthreads();
    float inv = 1.0f / dsh;
    for (int i = start + t; i < end; i += 256) out[i] *= inv;   // exclusive range: race-free RMW
}

extern "C" void kernel_launch(void* const* d_in, const int* in_sizes, int n_in,
                              void* d_out, int out_size, void* d_ws, size_t ws_size,
                              hipStream_t stream) {
    const float* x  = (const float*)d_in[0];
    const int*   nb = (const int*)d_in[1];
    const float* ga = (const float*)d_in[2];
    const float* Wg = (const float*)d_in[3];
    const float* bg = (const float*)d_in[4];
    const float* Wn = (const float*)d_in[5];
    const float* bn = (const float*)d_in[6];
    const float* Wa = (const float*)d_in[7];
    const float* ba = (const float*)d_in[8];
    float* outp = (float*)d_out;
    (void)d_ws; (void)ws_size;                   // ZERO workspace use (fill-poison probe)

    hipLaunchKernelGGL(node_kernel, dim3((N_NODES_C + 255) / 256), dim3(256), 0, stream,
                       x, nb, ga, Wg, bg, Wn, bn, Wa, ba, outp);
    hipLaunchKernelGGL(fin_kernel, dim3(N_GRAPHS_C), dim3(256), 0, stream,
                       nb, outp);
}

// Round 5
// 380.914 us; speedup vs baseline: 1.0417x; 1.0417x over previous
//
#include <hip/hip_runtime.h>
#include <hip/hip_bf16.h>
#include <stdint.h>

#define N_NODES_C 1000000
#define N_GRAPHS_C 4096
#define NTILES 15625      // 64-node tiles, exact
#define NODE_GRID 1024    // persistent blocks: exactly 4 per CU
#define SPAN 96           // block-local denom table: ~1024 consecutive nodes span ~4-7 graphs

typedef __attribute__((ext_vector_type(8))) __bf16 bf16x8;
typedef __attribute__((ext_vector_type(2))) __bf16 bf16x2;
typedef __attribute__((ext_vector_type(4))) float f32x4;

__device__ __forceinline__ unsigned short f2bf(float f) {
    union { float f; unsigned int u; } v; v.f = f;
    unsigned int r = v.u + 0x7FFFu + ((v.u >> 16) & 1u);   // RNE
    return (unsigned short)(r >> 16);
}
__device__ __forceinline__ unsigned int pack2(float a, float b) {
#if __has_builtin(__builtin_amdgcn_cvt_pk_bf16_f32)
    bf16x2 r = __builtin_amdgcn_cvt_pk_bf16_f32(a, b);
    union { bf16x2 v; unsigned int u; } cv; cv.v = r;
    return cv.u;
#else
    return (unsigned int)f2bf(a) | ((unsigned int)f2bf(b) << 16);
#endif
}

// Stage 0 (lean, 64 blocks): rank-3 factorization M = Wg@Wn_bot (3x64),
// C0 = bn + bg@Wn_bot; then c[b] = C0 + ga[b]@M for 64 graphs per block.
// Block 0 additionally emits BT (Wn_top^T in bf16); each block zeroes 64 denoms.
__global__ __launch_bounds__(256) void stage0_kernel(
    const float* __restrict__ ga, const float* __restrict__ Wg,
    const float* __restrict__ bg, const float* __restrict__ Wn,
    const float* __restrict__ bn,
    float* __restrict__ c, unsigned short* __restrict__ BT,
    float* __restrict__ denom)
{
    __shared__ float Wns[64 * 64];   // Wn rows 64..127 (16 KB)
    __shared__ float Ms[4][64];      // rows 0..2 = M[m][j]; row 3 = C0[j]
    int t = threadIdx.x;
#pragma unroll
    for (int i = 0; i < 4; ++i)
        ((float4*)Wns)[t + i * 256] = ((const float4*)(Wn + 64 * 64))[t + i * 256];
    if (blockIdx.x == 0) {
#pragma unroll
        for (int i = 0; i < 16; ++i) {
            int flat = t * 16 + i;           // BT[n][k] = Wn[k][n]
            int n = flat >> 6, k = flat & 63;
            BT[flat] = f2bf(Wn[k * 64 + n]);
        }
    }
    __syncthreads();
    {
        int m = t >> 6, j = t & 63;
        float accv;
        if (m == 3) {
            accv = bn[j];
#pragma unroll 16
            for (int k = 0; k < 64; ++k) accv += bg[k] * Wns[k * 64 + j];
        } else {
            accv = 0.f;
#pragma unroll 16
            for (int k = 0; k < 64; ++k) accv += Wg[m * 64 + k] * Wns[k * 64 + j];
        }
        Ms[m][j] = accv;
    }
    __syncthreads();
    int gl = t >> 6, j = t & 63;
    float m0 = Ms[0][j], m1 = Ms[1][j], m2 = Ms[2][j], c0v = Ms[3][j];
#pragma unroll
    for (int i = 0; i < 16; ++i) {
        int b = blockIdx.x * 64 + i * 4 + gl;
        c[b * 64 + j] = c0v + ga[b * 3] * m0 + ga[b * 3 + 1] * m1 + ga[b * 3 + 2] * m2;
    }
    if (t < 64) denom[blockIdx.x * 64 + t] = 0.0f;
}

// Persistent node kernel: 1024 blocks x 256 thr (4 blocks/CU co-resident via
// __launch_bounds__(256,4) + tiny LDS). Block owns a CONTIGUOUS run of 15-16
// 64-node tiles; wave w handles 16-node chunks w, w+4, ... with explicit
// next-chunk prefetch so HBM streams under the transcendental epilogue.
// Setup (B-frags/wa) and part[]-zero/flush barriers paid once per block (x15625 -> x1024).
__global__ __launch_bounds__(256, 4) void node_kernel(
    const float* __restrict__ x, const int* __restrict__ nb,
    const float* __restrict__ c, const unsigned short* __restrict__ BT,
    const float* __restrict__ Wa, const float* __restrict__ ba,
    float* __restrict__ e, float* __restrict__ denom)
{
    __shared__ float part[SPAN];
    int t = threadIdx.x;
    int wave = t >> 6, lane = t & 63;
    int quad = lane >> 4, l15 = lane & 15;

    int b = blockIdx.x;
    int q = NTILES / NODE_GRID, r = NTILES % NODE_GRID;     // q=15, r=265
    int tstart = b * q + (b < r ? b : r);
    int tcount = q + (b < r ? 1 : 0);
    int node0 = tstart * 64;
    int chunks = tcount * 4;                 // 16-node wave-chunks in this block

    bool is64 = nb[N_NODES_C - 1] < 1024;    // int64 low/high-word layout vs int32
    int g0 = is64 ? nb[2L * node0] : nb[node0];

    if (t < SPAN) part[t] = 0.0f;

    // Per-block invariants: B fragments B[k][n] (lane: n=l15+16*nt, k=quad*8+j+32*kh)
    bf16x8 b0[4], b1[4];
#pragma unroll
    for (int nt = 0; nt < 4; ++nt) {
        b0[nt] = *(const bf16x8*)&BT[(nt * 16 + l15) * 64 + quad * 8];
        b1[nt] = *(const bf16x8*)&BT[(nt * 16 + l15) * 64 + quad * 8 + 32];
    }
    float wa[4];
    float bav = ba[0];
#pragma unroll
    for (int nt = 0; nt < 4; ++nt) wa[nt] = Wa[nt * 16 + l15];

    __syncthreads();                         // part[] zeroed before any leader atomics

    // Software pipeline: prefetch chunk j=wave, then loop {prefetch j+4; compute j}
    int j = wave;
    float4 a0, a1, a2, a3; int segc = 0;
    if (j < chunks) {
        int base = node0 + j * 16;
        const float4* xp = (const float4*)(x + (long)(base + l15) * 64);
        a0 = xp[quad * 2];
        a1 = xp[quad * 2 + 1];
        a2 = xp[8 + quad * 2];
        a3 = xp[8 + quad * 2 + 1];
        segc = is64 ? nb[2L * (base + l15)] : nb[base + l15];
    }
    while (j < chunks) {
        int jn = j + 4;
        float4 n0, n1, n2, n3; int segn = 0;
        if (jn < chunks) {                   // issue next-chunk loads NOW (fly under epilogue)
            int nbase = node0 + jn * 16;
            const float4* xp = (const float4*)(x + (long)(nbase + l15) * 64);
            n0 = xp[quad * 2];
            n1 = xp[quad * 2 + 1];
            n2 = xp[8 + quad * 2];
            n3 = xp[8 + quad * 2 + 1];
            segn = is64 ? nb[2L * (nbase + l15)] : nb[nbase + l15];
        } else {
            n0 = n1 = n2 = n3 = make_float4(0.f, 0.f, 0.f, 0.f);
        }

        int base = node0 + j * 16;
        int sg0 = __shfl(segc, quad * 4 + 0, 64);
        int sg1 = __shfl(segc, quad * 4 + 1, 64);
        int sg2 = __shfl(segc, quad * 4 + 2, 64);
        int sg3 = __shfl(segc, quad * 4 + 3, 64);

        union { bf16x8 v; unsigned int u[4]; } A0, A1;
        A0.u[0] = pack2(a0.x, a0.y); A0.u[1] = pack2(a0.z, a0.w);
        A0.u[2] = pack2(a1.x, a1.y); A0.u[3] = pack2(a1.z, a1.w);
        A1.u[0] = pack2(a2.x, a2.y); A1.u[1] = pack2(a2.z, a2.w);
        A1.u[2] = pack2(a3.x, a3.y); A1.u[3] = pack2(a3.z, a3.w);

        f32x4 acc[4];
#pragma unroll
        for (int nt = 0; nt < 4; ++nt) {
            acc[nt] = (f32x4){0.f, 0.f, 0.f, 0.f};
            acc[nt] = __builtin_amdgcn_mfma_f32_16x16x32_bf16(A0.v, b0[nt], acc[nt], 0, 0, 0);
            acc[nt] = __builtin_amdgcn_mfma_f32_16x16x32_bf16(A1.v, b1[nt], acc[nt], 0, 0, 0);
        }

        // Epilogue. C/D layout: col = l15 + 16*nt, rows = base + quad*4 + reg
        bool uni = (sg0 == sg3);             // sorted -> ends equal => all equal
        float sp0 = 0.f, sp1 = 0.f, sp2 = 0.f, sp3 = 0.f;
#pragma unroll
        for (int nt = 0; nt < 4; ++nt) {
            int col = nt * 16 + l15;
            float c0, c1, c2, c3;
            if (uni) { c0 = c[sg0 * 64 + col]; c1 = c0; c2 = c0; c3 = c0; }
            else {
                c0 = c[sg0 * 64 + col]; c1 = c[sg1 * 64 + col];
                c2 = c[sg2 * 64 + col]; c3 = c[sg3 * 64 + col];
            }
            float y0 = acc[nt].x + c0, y1 = acc[nt].y + c1;
            float y2 = acc[nt].z + c2, y3 = acc[nt].w + c3;
            sp0 += __logf(1.f + __expf(y0)) * wa[nt];
            sp1 += __logf(1.f + __expf(y1)) * wa[nt];
            sp2 += __logf(1.f + __expf(y2)) * wa[nt];
            sp3 += __logf(1.f + __expf(y3)) * wa[nt];
        }
#pragma unroll
        for (int off = 1; off < 16; off <<= 1) {    // xor 1,2,4,8 stays inside the quad
            sp0 += __shfl_xor(sp0, off, 64);
            sp1 += __shfl_xor(sp1, off, 64);
            sp2 += __shfl_xor(sp2, off, 64);
            sp3 += __shfl_xor(sp3, off, 64);
        }
        float e0 = __expf(sp0 + bav), e1 = __expf(sp1 + bav);
        float e2 = __expf(sp2 + bav), e3 = __expf(sp3 + bav);
        if (l15 == 0) {
            *(float4*)&e[base + quad * 4] = make_float4(e0, e1, e2, e3);
            // merge runs, LDS-aggregate (global fallback only if span exceeded: ~never)
            float s = e0; int cur = sg0;
            if (sg1 == cur) s += e1; else {
                unsigned int i0 = cur - g0;
                if (i0 < SPAN) atomicAdd(&part[i0], s); else atomicAdd(&denom[cur], s);
                cur = sg1; s = e1;
            }
            if (sg2 == cur) s += e2; else {
                unsigned int i0 = cur - g0;
                if (i0 < SPAN) atomicAdd(&part[i0], s); else atomicAdd(&denom[cur], s);
                cur = sg2; s = e2;
            }
            if (sg3 == cur) s += e3; else {
                unsigned int i0 = cur - g0;
                if (i0 < SPAN) atomicAdd(&part[i0], s); else atomicAdd(&denom[cur], s);
                cur = sg3; s = e3;
            }
            unsigned int i0 = cur - g0;
            if (i0 < SPAN) atomicAdd(&part[i0], s); else atomicAdd(&denom[cur], s);
        }

        a0 = n0; a1 = n1; a2 = n2; a3 = n3; segc = segn;
        j = jn;
    }

    __syncthreads();                         // all waves done with part[]
    if (t < SPAN) {
        float v = part[t];
        if (v != 0.0f) atomicAdd(&denom[g0 + t], v);
    }
}

// Finalize: w = e / denom[seg]
__global__ __launch_bounds__(256) void fin_kernel(
    const float* __restrict__ e, const int* __restrict__ nb,
    const float* __restrict__ denom, float* __restrict__ out)
{
    long node0 = (long)(blockIdx.x * 256 + threadIdx.x) * 4;
    if (node0 >= N_NODES_C) return;
    bool is64 = nb[N_NODES_C - 1] < 1024;
    float4 ev = *(const float4*)&e[node0];
    int s0, s1, s2, s3;
    if (is64) {
        int4 a = *(const int4*)&nb[2 * node0];
        int4 b = *(const int4*)&nb[2 * node0 + 4];
        s0 = a.x; s1 = a.z; s2 = b.x; s3 = b.z;
    } else {
        int4 a = *(const int4*)&nb[node0];
        s0 = a.x; s1 = a.y; s2 = a.z; s3 = a.w;
    }
    float4 w;
    w.x = ev.x / denom[s0];
    w.y = ev.y / denom[s1];
    w.z = ev.z / denom[s2];
    w.w = ev.w / denom[s3];
    *(float4*)&out[node0] = w;
}

extern "C" void kernel_launch(void* const* d_in, const int* in_sizes, int n_in,
                              void* d_out, int out_size, void* d_ws, size_t ws_size,
                              hipStream_t stream) {
    const float* x  = (const float*)d_in[0];
    const int*   nb = (const int*)d_in[1];
    const float* ga = (const float*)d_in[2];
    const float* Wg = (const float*)d_in[3];
    const float* bg = (const float*)d_in[4];
    const float* Wn = (const float*)d_in[5];
    const float* bn = (const float*)d_in[6];
    const float* Wa = (const float*)d_in[7];
    const float* ba = (const float*)d_in[8];

    char* ws = (char*)d_ws;
    float* e            = (float*)(ws);                              // 4,000,000 B
    float* c            = (float*)(ws + 4194304);                    // 1 MB
    unsigned short* BT  = (unsigned short*)(ws + 4194304 + 1048576); // 8 KB
    float* denom        = (float*)(ws + 4194304 + 1048576 + 8192);   // 16 KB

    hipLaunchKernelGGL(stage0_kernel, dim3(N_GRAPHS_C / 64), dim3(256), 0, stream,
                       ga, Wg, bg, Wn, bn, c, BT, denom);
    hipLaunchKernelGGL(node_kernel, dim3(NODE_GRID), dim3(256), 0, stream,
                       x, nb, c, BT, Wa, ba, e, denom);
    hipLaunchKernelGGL(fin_kernel, dim3((N_NODES_C / 4 + 255) / 256), dim3(256), 0, stream,
                       e, nb, denom, (float*)d_out);
}